// Round 1
// baseline (611.770 us; speedup 1.0000x reference)
//
#include <hip/hip_runtime.h>
#include <hip/hip_bf16.h>
#include <stdint.h>

#define N_NODES 100000
#define N_EDGES 1600000
#define DIM     128
#define ALPHA   0.01f
#define BN_EPS  1e-5f

typedef __bf16 bf16x8 __attribute__((ext_vector_type(8)));
typedef float  f32x4  __attribute__((ext_vector_type(4)));

// ---- workspace layout (bytes) ----
static const size_t OFF_FLAGS    = 0;          // 2 ints: [0]=idx64, [1]=isf32
static const size_t OFF_SUM      = 512;        // 128 f32
static const size_t OFF_SUMSQ    = 1024;       // 128 f32
static const size_t OFF_BLOCKTOT = 1536;       // 49 ints
static const size_t OFF_CNT      = 4096;       // 100000 ints  (end 404096)
static const size_t OFF_OFFS     = 404480;     // 100000 ints  (end 804480)
static const size_t OFF_WPTR     = 804864;     // 100000 ints  (end 1204864)
static const size_t OFF_CSR      = 1205248;    // 1.6M ints    (end 7605248)
static const size_t OFF_BFRAG    = 7605760;    // 64 KiB       (end 7671296)
static const size_t OFF_A        = 7671296;    // 100000x256 bf16 (end 58871296)
static const size_t OFF_H        = 58871296;   // 100000x128 f32  (end 110071296)

__device__ __forceinline__ float bf2f(unsigned short h) {
    return __uint_as_float(((unsigned int)h) << 16);
}
__device__ __forceinline__ unsigned short f2bf(float f) {
    unsigned int u = __float_as_uint(f);
    u = u + 0x7fffu + ((u >> 16) & 1u);   // round-to-nearest-even
    return (unsigned short)(u >> 16);
}
__device__ __forceinline__ float loadS(const void* p, int i, int isf32) {
    return isf32 ? ((const float*)p)[i] : bf2f(((const unsigned short*)p)[i]);
}
__device__ __forceinline__ int edge_at(const void* e, long long i, int idx64) {
    return idx64 ? (int)((const long long*)e)[i] : ((const int*)e)[i];
}

// ---- dtype detection: idx64 from high-word zeros; bf16 float from exponent stats ----
__global__ void detect_kernel(const unsigned int* xw, const unsigned int* ew, int* flags) {
    __shared__ int s_nonzero_hi, s_bflike;
    int t = threadIdx.x;
    if (t == 0) { s_nonzero_hi = 0; s_bflike = 0; }
    __syncthreads();
    // int64 hypothesis: words at odd positions (high halves) are all zero (values < 2^32)
    if (ew[2 * t + 1] != 0) atomicAdd(&s_nonzero_hi, 1);
    // bf16 hypothesis on x: low 16 bits of each word is a bf16 of ~N(0,1):
    // its exponent field ((w>>7)&0xff) concentrates in [110,140]; for fp32 these are
    // uniform mantissa bits (~12% in range).
    unsigned int w = xw[t];
    unsigned int e = (w >> 7) & 0xffu;
    if ((e >= 110u && e <= 140u) || ((w & 0xffffu) == 0u)) atomicAdd(&s_bflike, 1);
    __syncthreads();
    if (t == 0) {
        flags[0] = (s_nonzero_hi == 0) ? 1 : 0;  // idx64
        flags[1] = (s_bflike > 512) ? 0 : 1;     // isf32
    }
}

// ---- degree histogram ----
__global__ void hist_kernel(const void* edges, int* cnt, const int* flags) {
    int idx64 = flags[0];
    int i = blockIdx.x * 256 + threadIdx.x;
    int d = edge_at(edges, (long long)N_EDGES + i, idx64);
    atomicAdd(&cnt[d], 1);
}

// ---- exclusive scan of cnt -> offs (3 kernels) ----
__global__ void scan1_kernel(const int* cnt, int* offs, int* blockTot) {
    __shared__ int sdata[256];
    int b = blockIdx.x, t = threadIdx.x;
    int base = b * 2048 + t * 8;
    int v[8]; int s = 0;
    #pragma unroll
    for (int i = 0; i < 8; i++) {
        int idx = base + i;
        v[i] = (idx < N_NODES) ? cnt[idx] : 0;
        s += v[i];
    }
    sdata[t] = s;
    __syncthreads();
    for (int off = 1; off < 256; off <<= 1) {
        int x = (t >= off) ? sdata[t - off] : 0;
        __syncthreads();
        sdata[t] += x;
        __syncthreads();
    }
    int run = sdata[t] - s;  // exclusive within block
    if (t == 255) blockTot[b] = sdata[255];
    #pragma unroll
    for (int i = 0; i < 8; i++) {
        int idx = base + i;
        if (idx < N_NODES) offs[idx] = run;
        run += v[i];
    }
}
__global__ void scan2_kernel(int* blockTot, int nb) {
    int t = threadIdx.x;
    int v = (t < nb) ? blockTot[t] : 0;
    int orig = v;
    for (int off = 1; off < 64; off <<= 1) {
        int u = __shfl_up(v, off, 64);
        if (t >= off) v += u;
    }
    if (t < nb) blockTot[t] = v - orig;  // exclusive
}
__global__ void scan3_kernel(int* offs, const int* blockTot, int* wptr) {
    int i = blockIdx.x * 256 + threadIdx.x;
    if (i < N_NODES) {
        int v = offs[i] + blockTot[i >> 11];
        offs[i] = v;
        wptr[i] = v;
    }
}

// ---- CSR fill ----
__global__ void fill_kernel(const void* edges, int* wptr, int* csr, const int* flags) {
    int idx64 = flags[0];
    int i = blockIdx.x * 256 + threadIdx.x;
    int s = edge_at(edges, i, idx64);
    int d = edge_at(edges, (long long)N_EDGES + i, idx64);
    int pos = atomicAdd(&wptr[d], 1);
    csr[pos] = s;
}

// ---- aggregation: one wave per node; write bf16 A = [mean | x] ----
__global__ __launch_bounds__(256) void agg_kernel(const void* x, const int* csr,
                                                  const int* offs, const int* cnt,
                                                  unsigned int* A32, const int* flags) {
    int isf32 = flags[1];
    int node = blockIdx.x * 4 + (threadIdx.x >> 6);
    int lane = threadIdx.x & 63;
    int beg = offs[node];
    int c = cnt[node];
    float a0 = 0.f, a1 = 0.f, x0, x1;
    if (isf32) {
        const float* xf = (const float*)x;
        for (int j = 0; j < c; j++) {
            int s = csr[beg + j];
            float2 v = *(const float2*)(xf + (size_t)s * DIM + 2 * lane);
            a0 += v.x; a1 += v.y;
        }
        float2 xv = *(const float2*)(xf + (size_t)node * DIM + 2 * lane);
        x0 = xv.x; x1 = xv.y;
    } else {
        const unsigned short* xb = (const unsigned short*)x;
        for (int j = 0; j < c; j++) {
            int s = csr[beg + j];
            unsigned int w = *(const unsigned int*)(xb + (size_t)s * DIM + 2 * lane);
            a0 += bf2f((unsigned short)(w & 0xffffu));
            a1 += bf2f((unsigned short)(w >> 16));
        }
        unsigned int w = *(const unsigned int*)(xb + (size_t)node * DIM + 2 * lane);
        x0 = bf2f((unsigned short)(w & 0xffffu));
        x1 = bf2f((unsigned short)(w >> 16));
    }
    float inv = 1.0f / (float)max(c, 1);
    float m0 = a0 * inv, m1 = a1 * inv;
    unsigned int mp = (unsigned int)f2bf(m0) | ((unsigned int)f2bf(m1) << 16);
    unsigned int xp = (unsigned int)f2bf(x0) | ((unsigned int)f2bf(x1) << 16);
    A32[(size_t)node * 128 + lane] = mp;
    A32[(size_t)node * 128 + 64 + lane] = xp;
}

// ---- pre-swizzle B into MFMA fragment order: Bfrag[t][s][lane][j] ----
__global__ void bprep_kernel(const void* W_l, const void* W_r,
                             unsigned short* bfrag, const int* flags) {
    int isf32 = flags[1];
    for (int g = threadIdx.x; g < 32768; g += 256) {
        int j    = g & 7;
        int lane = (g >> 3) & 63;
        int s    = (g >> 9) & 7;
        int t    = (g >> 12) & 7;
        int n = t * 16 + (lane & 15);
        int k = s * 32 + ((lane >> 4) & 3) * 8 + j;
        float v = (k < DIM) ? loadS(W_l, n * DIM + k, isf32)
                            : loadS(W_r, n * DIM + (k - DIM), isf32);
        bfrag[g] = f2bf(v);
    }
}

// ---- persistent MFMA GEMM: H[100000x128] = A[100000x256] @ B[256x128] + b_l ----
__global__ __launch_bounds__(256) void gemm_kernel(const unsigned short* A,
                                                   const unsigned short* Bfrag_g,
                                                   const void* b_l, float* H,
                                                   const int* flags) {
    __shared__ unsigned short lds[32768];  // 64 KiB, fragment-ordered B
    int isf32 = flags[1];
    {
        const uint4* src = (const uint4*)Bfrag_g;
        uint4* dst = (uint4*)lds;
        for (int i = threadIdx.x; i < 4096; i += 256) dst[i] = src[i];
    }
    __syncthreads();
    int wave = threadIdx.x >> 6, lane = threadIdx.x & 63;
    int lm = lane & 15, lq = lane >> 4;
    float bv[8];
    #pragma unroll
    for (int t = 0; t < 8; t++) bv[t] = loadS(b_l, t * 16 + lm, isf32);

    for (int m0 = blockIdx.x * 64; m0 < N_NODES; m0 += gridDim.x * 64) {
        int rowA = m0 + wave * 16 + lm;
        if (rowA >= N_NODES) rowA = N_NODES - 1;
        const unsigned short* arow = A + (size_t)rowA * 256 + lq * 8;
        f32x4 acc[8];
        #pragma unroll
        for (int t = 0; t < 8; t++) acc[t] = (f32x4){0.f, 0.f, 0.f, 0.f};
        #pragma unroll
        for (int s = 0; s < 8; s++) {
            bf16x8 a = *(const bf16x8*)(arow + s * 32);
            #pragma unroll
            for (int t = 0; t < 8; t++) {
                bf16x8 b = *(const bf16x8*)(lds + ((t * 8 + s) * 64 + lane) * 8);
                acc[t] = __builtin_amdgcn_mfma_f32_16x16x32_bf16(a, b, acc[t], 0, 0, 0);
            }
        }
        #pragma unroll
        for (int t = 0; t < 8; t++) {
            int col = t * 16 + lm;
            #pragma unroll
            for (int r = 0; r < 4; r++) {
                int ro = m0 + wave * 16 + lq * 4 + r;
                if (ro < N_NODES) H[(size_t)ro * DIM + col] = acc[t][r] + bv[t];
            }
        }
    }
}

// ---- BN stats: column sums / sumsq ----
__global__ __launch_bounds__(256) void bn_stats_kernel(const float* H, float* gsum, float* gsumsq) {
    __shared__ float sd[256], sd2[256];
    int tid = threadIdx.x;
    int col = tid & 127, half = tid >> 7;
    float s = 0.f, s2 = 0.f;
    for (int row = blockIdx.x * 2 + half; row < N_NODES; row += gridDim.x * 2) {
        float v = H[(size_t)row * DIM + col];
        s += v; s2 += v * v;
    }
    sd[tid] = s; sd2[tid] = s2;
    __syncthreads();
    if (tid < 128) {
        atomicAdd(&gsum[col], sd[tid] + sd[tid + 128]);
        atomicAdd(&gsumsq[col], sd2[tid] + sd2[tid + 128]);
    }
}

// ---- normalize + LeakyReLU, write out (dtype per flag) ----
__global__ __launch_bounds__(256) void bn_norm_kernel(const float* H, const float* gsum,
                                                      const float* gsumsq, const void* gamma,
                                                      const void* beta, void* out,
                                                      const int* flags) {
    __shared__ float sc[128], sh[128];
    int isf32 = flags[1];
    int tid = threadIdx.x;
    if (tid < 128) {
        const float invN = 1.0f / (float)N_NODES;
        float mu = gsum[tid] * invN;
        float var = gsumsq[tid] * invN - mu * mu;
        float rstd = rsqrtf(var + BN_EPS);
        float g = loadS(gamma, tid, isf32);
        float b = loadS(beta, tid, isf32);
        sc[tid] = g * rstd;
        sh[tid] = b - mu * g * rstd;
    }
    __syncthreads();
    size_t idx = (size_t)blockIdx.x * 256 + tid;
    size_t i4 = idx * 4;
    if (i4 >= (size_t)N_NODES * DIM) return;
    float4 h = *(const float4*)(H + i4);
    int c0 = (int)(i4 & 127);
    float o0 = h.x * sc[c0 + 0] + sh[c0 + 0];
    float o1 = h.y * sc[c0 + 1] + sh[c0 + 1];
    float o2 = h.z * sc[c0 + 2] + sh[c0 + 2];
    float o3 = h.w * sc[c0 + 3] + sh[c0 + 3];
    o0 = (o0 >= 0.f) ? o0 : ALPHA * o0;
    o1 = (o1 >= 0.f) ? o1 : ALPHA * o1;
    o2 = (o2 >= 0.f) ? o2 : ALPHA * o2;
    o3 = (o3 >= 0.f) ? o3 : ALPHA * o3;
    if (isf32) {
        float4 o = make_float4(o0, o1, o2, o3);
        *(float4*)((float*)out + i4) = o;
    } else {
        uint2 u;
        u.x = (unsigned int)f2bf(o0) | ((unsigned int)f2bf(o1) << 16);
        u.y = (unsigned int)f2bf(o2) | ((unsigned int)f2bf(o3) << 16);
        *(uint2*)((unsigned short*)out + i4) = u;
    }
}

extern "C" void kernel_launch(void* const* d_in, const int* in_sizes, int n_in,
                              void* d_out, int out_size, void* d_ws, size_t ws_size,
                              hipStream_t stream) {
    const void* x     = d_in[0];
    const void* eidx  = d_in[1];
    const void* W_l   = d_in[2];
    const void* b_l   = d_in[3];
    const void* W_r   = d_in[4];
    const void* gamma = d_in[5];
    const void* beta  = d_in[6];
    char* ws = (char*)d_ws;
    int* flags = (int*)(ws + OFF_FLAGS);
    float* gsum = (float*)(ws + OFF_SUM);
    float* gsumsq = (float*)(ws + OFF_SUMSQ);
    int* blockTot = (int*)(ws + OFF_BLOCKTOT);
    int* cnt = (int*)(ws + OFF_CNT);
    int* offs = (int*)(ws + OFF_OFFS);
    int* wptr = (int*)(ws + OFF_WPTR);
    int* csr = (int*)(ws + OFF_CSR);
    unsigned short* bfrag = (unsigned short*)(ws + OFF_BFRAG);
    unsigned short* A = (unsigned short*)(ws + OFF_A);
    float* H = (float*)(ws + OFF_H);

    // zero flags/sums/blockTot/cnt
    hipMemsetAsync(ws, 0, OFF_CNT + (size_t)N_NODES * sizeof(int), stream);
    detect_kernel<<<1, 1024, 0, stream>>>((const unsigned int*)x, (const unsigned int*)eidx, flags);
    hist_kernel<<<N_EDGES / 256, 256, 0, stream>>>(eidx, cnt, flags);
    scan1_kernel<<<49, 256, 0, stream>>>(cnt, offs, blockTot);
    scan2_kernel<<<1, 64, 0, stream>>>(blockTot, 49);
    scan3_kernel<<<(N_NODES + 255) / 256, 256, 0, stream>>>(offs, blockTot, wptr);
    fill_kernel<<<N_EDGES / 256, 256, 0, stream>>>(eidx, wptr, csr, flags);
    bprep_kernel<<<1, 256, 0, stream>>>(W_l, W_r, bfrag, flags);
    agg_kernel<<<N_NODES / 4, 256, 0, stream>>>(x, csr, offs, cnt, (unsigned int*)A, flags);
    gemm_kernel<<<512, 256, 0, stream>>>(A, bfrag, b_l, H, flags);
    bn_stats_kernel<<<512, 256, 0, stream>>>(H, gsum, gsumsq);
    bn_norm_kernel<<<12500, 256, 0, stream>>>(H, gsum, gsumsq, gamma, beta, d_out, flags);
}

// Round 2
// 487.042 us; speedup vs baseline: 1.2561x; 1.2561x over previous
//
#include <hip/hip_runtime.h>
#include <hip/hip_bf16.h>
#include <stdint.h>

#define N_NODES 100000
#define N_EDGES 1600000
#define DIM     128
#define ALPHA   0.01f
#define BN_EPS  1e-5f

typedef __bf16 bf16x8 __attribute__((ext_vector_type(8)));
typedef float  f32x4  __attribute__((ext_vector_type(4)));

// ---- workspace layout (bytes) ----
static const size_t OFF_FLAGS    = 0;          // 2 ints: [0]=idx64, [1]=isf32
static const size_t OFF_SUM      = 512;        // 128 f32
static const size_t OFF_SUMSQ    = 1024;       // 128 f32
static const size_t OFF_BLOCKTOT = 1536;       // 49 ints
static const size_t OFF_CNT      = 4096;       // 100000 ints  (end 404096)
static const size_t OFF_OFFS     = 404480;     // 100000 ints  (end 804480)
static const size_t OFF_WPTR     = 804864;     // 100000 ints  (end 1204864)
static const size_t OFF_CSR      = 1205248;    // 1.6M ints    (end 7605248)
static const size_t OFF_BFRAG    = 7605760;    // 64 KiB       (end 7671296)
static const size_t OFF_A        = 7671296;    // 100000x256 bf16 (end 58871296)
static const size_t OFF_H        = 58871296;   // 100000x128 f32  (end 110071296)

__device__ __forceinline__ float bf2f(unsigned short h) {
    return __uint_as_float(((unsigned int)h) << 16);
}
__device__ __forceinline__ float bflo(unsigned int w) {
    return __uint_as_float(w << 16);
}
__device__ __forceinline__ float bfhi(unsigned int w) {
    return __uint_as_float(w & 0xffff0000u);
}
__device__ __forceinline__ unsigned short f2bf(float f) {
    unsigned int u = __float_as_uint(f);
    u = u + 0x7fffu + ((u >> 16) & 1u);   // round-to-nearest-even
    return (unsigned short)(u >> 16);
}
__device__ __forceinline__ unsigned int pack2(float a, float b) {
    return (unsigned int)f2bf(a) | ((unsigned int)f2bf(b) << 16);
}
__device__ __forceinline__ float loadS(const void* p, int i, int isf32) {
    return isf32 ? ((const float*)p)[i] : bf2f(((const unsigned short*)p)[i]);
}
__device__ __forceinline__ int edge_at(const void* e, long long i, int idx64) {
    return idx64 ? (int)((const long long*)e)[i] : ((const int*)e)[i];
}

// ---- dtype detection: idx64 from high-word zeros; bf16 float from exponent stats ----
__global__ void detect_kernel(const unsigned int* xw, const unsigned int* ew, int* flags) {
    __shared__ int s_nonzero_hi, s_bflike;
    int t = threadIdx.x;
    if (t == 0) { s_nonzero_hi = 0; s_bflike = 0; }
    __syncthreads();
    if (ew[2 * t + 1] != 0) atomicAdd(&s_nonzero_hi, 1);
    unsigned int w = xw[t];
    unsigned int e = (w >> 7) & 0xffu;
    if ((e >= 110u && e <= 140u) || ((w & 0xffffu) == 0u)) atomicAdd(&s_bflike, 1);
    __syncthreads();
    if (t == 0) {
        flags[0] = (s_nonzero_hi == 0) ? 1 : 0;  // idx64
        flags[1] = (s_bflike > 512) ? 0 : 1;     // isf32
    }
}

// ---- degree histogram ----
__global__ void hist_kernel(const void* edges, int* cnt, const int* flags) {
    int idx64 = flags[0];
    int i = blockIdx.x * 256 + threadIdx.x;
    int d = edge_at(edges, (long long)N_EDGES + i, idx64);
    atomicAdd(&cnt[d], 1);
}

// ---- exclusive scan of cnt -> offs (3 kernels) ----
__global__ void scan1_kernel(const int* cnt, int* offs, int* blockTot) {
    __shared__ int sdata[256];
    int b = blockIdx.x, t = threadIdx.x;
    int base = b * 2048 + t * 8;
    int v[8]; int s = 0;
    #pragma unroll
    for (int i = 0; i < 8; i++) {
        int idx = base + i;
        v[i] = (idx < N_NODES) ? cnt[idx] : 0;
        s += v[i];
    }
    sdata[t] = s;
    __syncthreads();
    for (int off = 1; off < 256; off <<= 1) {
        int x = (t >= off) ? sdata[t - off] : 0;
        __syncthreads();
        sdata[t] += x;
        __syncthreads();
    }
    int run = sdata[t] - s;  // exclusive within block
    if (t == 255) blockTot[b] = sdata[255];
    #pragma unroll
    for (int i = 0; i < 8; i++) {
        int idx = base + i;
        if (idx < N_NODES) offs[idx] = run;
        run += v[i];
    }
}
__global__ void scan2_kernel(int* blockTot, int nb) {
    int t = threadIdx.x;
    int v = (t < nb) ? blockTot[t] : 0;
    int orig = v;
    for (int off = 1; off < 64; off <<= 1) {
        int u = __shfl_up(v, off, 64);
        if (t >= off) v += u;
    }
    if (t < nb) blockTot[t] = v - orig;  // exclusive
}
__global__ void scan3_kernel(int* offs, const int* blockTot, int* wptr) {
    int i = blockIdx.x * 256 + threadIdx.x;
    if (i < N_NODES) {
        int v = offs[i] + blockTot[i >> 11];
        offs[i] = v;
        wptr[i] = v;
    }
}

// ---- CSR fill ----
__global__ void fill_kernel(const void* edges, int* wptr, int* csr, const int* flags) {
    int idx64 = flags[0];
    int i = blockIdx.x * 256 + threadIdx.x;
    int s = edge_at(edges, i, idx64);
    int d = edge_at(edges, (long long)N_EDGES + i, idx64);
    int pos = atomicAdd(&wptr[d], 1);
    csr[pos] = s;
}

// ---- aggregation: one wave per node, 4 rows in flight via 16-lane quads, x2 unroll ----
// bf16: row = 256 B = 16 lanes x uint4. quad q handles edges j%4==q (two chunks).
// Writes ONLY the mean half of A (cols 0..127); gemm reads x directly for bf16.
__global__ __launch_bounds__(256) void agg_kernel(const void* x, const int* csr,
                                                  const int* offs, const int* cnt,
                                                  unsigned short* A, const int* flags) {
    int isf32 = flags[1];
    int node = blockIdx.x * 4 + (threadIdx.x >> 6);
    int lane = threadIdx.x & 63;
    int beg = offs[node];
    int c = cnt[node];
    float inv = 1.0f / (float)max(c, 1);

    if (!isf32) {
        const uint4* xb = (const uint4*)x;          // row = 16 uint4
        int quad = lane >> 4, ql = lane & 15;
        float acc[8];
        #pragma unroll
        for (int i = 0; i < 8; i++) acc[i] = 0.f;
        for (int jj = 0; jj < c; jj += 8) {
            int e0 = jj + quad, e1 = jj + 4 + quad;
            bool v0 = e0 < c, v1 = e1 < c;
            int s0 = csr[beg + (v0 ? e0 : 0)];
            int s1 = csr[beg + (v1 ? e1 : 0)];
            uint4 r0 = xb[(size_t)s0 * 16 + ql];
            uint4 r1 = xb[(size_t)s1 * 16 + ql];
            float m0 = v0 ? 1.f : 0.f, m1 = v1 ? 1.f : 0.f;
            acc[0] += m0 * bflo(r0.x); acc[1] += m0 * bfhi(r0.x);
            acc[2] += m0 * bflo(r0.y); acc[3] += m0 * bfhi(r0.y);
            acc[4] += m0 * bflo(r0.z); acc[5] += m0 * bfhi(r0.z);
            acc[6] += m0 * bflo(r0.w); acc[7] += m0 * bfhi(r0.w);
            acc[0] += m1 * bflo(r1.x); acc[1] += m1 * bfhi(r1.x);
            acc[2] += m1 * bflo(r1.y); acc[3] += m1 * bfhi(r1.y);
            acc[4] += m1 * bflo(r1.z); acc[5] += m1 * bfhi(r1.z);
            acc[6] += m1 * bflo(r1.w); acc[7] += m1 * bfhi(r1.w);
        }
        #pragma unroll
        for (int i = 0; i < 8; i++) {
            acc[i] += __shfl_xor(acc[i], 16, 64);
            acc[i] += __shfl_xor(acc[i], 32, 64);
        }
        if (quad == 0) {
            uint4 o;
            o.x = pack2(acc[0] * inv, acc[1] * inv);
            o.y = pack2(acc[2] * inv, acc[3] * inv);
            o.z = pack2(acc[4] * inv, acc[5] * inv);
            o.w = pack2(acc[6] * inv, acc[7] * inv);
            *(uint4*)(A + (size_t)node * 256 + ql * 8) = o;
        }
    } else {
        const float4* xf = (const float4*)x;        // row = 32 float4
        int half = lane >> 5, hl = lane & 31;
        float a0 = 0.f, a1 = 0.f, a2 = 0.f, a3 = 0.f;
        for (int jj = 0; jj < c; jj += 4) {
            int e0 = jj + half, e1 = jj + 2 + half;
            bool v0 = e0 < c, v1 = e1 < c;
            int s0 = csr[beg + (v0 ? e0 : 0)];
            int s1 = csr[beg + (v1 ? e1 : 0)];
            float4 r0 = xf[(size_t)s0 * 32 + hl];
            float4 r1 = xf[(size_t)s1 * 32 + hl];
            float m0 = v0 ? 1.f : 0.f, m1 = v1 ? 1.f : 0.f;
            a0 += m0 * r0.x + m1 * r1.x;
            a1 += m0 * r0.y + m1 * r1.y;
            a2 += m0 * r0.z + m1 * r1.z;
            a3 += m0 * r0.w + m1 * r1.w;
        }
        a0 += __shfl_xor(a0, 32, 64);
        a1 += __shfl_xor(a1, 32, 64);
        a2 += __shfl_xor(a2, 32, 64);
        a3 += __shfl_xor(a3, 32, 64);
        if (half == 0) {
            uint2 o;
            o.x = pack2(a0 * inv, a1 * inv);
            o.y = pack2(a2 * inv, a3 * inv);
            *(uint2*)(A + (size_t)node * 256 + hl * 4) = o;
        } else {
            float4 xv = xf[(size_t)node * 32 + hl];
            uint2 o;
            o.x = pack2(xv.x, xv.y);
            o.y = pack2(xv.z, xv.w);
            *(uint2*)(A + (size_t)node * 256 + 128 + hl * 4) = o;
        }
    }
}

// ---- pre-swizzle B into MFMA fragment order: Bfrag[t][s][lane][j] ----
__global__ void bprep_kernel(const void* W_l, const void* W_r,
                             unsigned short* bfrag, const int* flags) {
    int isf32 = flags[1];
    int g = blockIdx.x * 256 + threadIdx.x;
    int j    = g & 7;
    int lane = (g >> 3) & 63;
    int s    = (g >> 9) & 7;
    int t    = (g >> 12) & 7;
    int n = t * 16 + (lane & 15);
    int k = s * 32 + ((lane >> 4) & 3) * 8 + j;
    float v = (k < DIM) ? loadS(W_l, n * DIM + k, isf32)
                        : loadS(W_r, n * DIM + (k - DIM), isf32);
    bfrag[g] = f2bf(v);
}

// ---- persistent MFMA GEMM + fused BN stats ----
// H[100000x128] = A[:, 0:128]@W_l^T-part + x@W_r^T-part + b_l
// For bf16 input, x half of the K dim is read straight from x.
__global__ __launch_bounds__(256) void gemm_kernel(const unsigned short* A,
                                                   const void* x,
                                                   const unsigned short* Bfrag_g,
                                                   const void* b_l, float* H,
                                                   float* gsum, float* gsumsq,
                                                   const int* flags) {
    __shared__ unsigned short lds[32768];  // 64 KiB, fragment-ordered B
    __shared__ float sstat[2][128];
    int isf32 = flags[1];
    {
        const uint4* src = (const uint4*)Bfrag_g;
        uint4* dst = (uint4*)lds;
        for (int i = threadIdx.x; i < 4096; i += 256) dst[i] = src[i];
        if (threadIdx.x < 128) { sstat[0][threadIdx.x] = 0.f; sstat[1][threadIdx.x] = 0.f; }
    }
    __syncthreads();
    int wave = threadIdx.x >> 6, lane = threadIdx.x & 63;
    int lm = lane & 15, lq = lane >> 4;
    float bv[8];
    #pragma unroll
    for (int t = 0; t < 8; t++) bv[t] = loadS(b_l, t * 16 + lm, isf32);
    float st1[8], st2[8];
    #pragma unroll
    for (int t = 0; t < 8; t++) { st1[t] = 0.f; st2[t] = 0.f; }
    const unsigned short* xus = (const unsigned short*)x;

    for (int m0 = blockIdx.x * 64; m0 < N_NODES; m0 += gridDim.x * 64) {
        int rowA = m0 + wave * 16 + lm;
        if (rowA >= N_NODES) rowA = N_NODES - 1;
        const unsigned short* amean = A + (size_t)rowA * 256 + lq * 8;
        const unsigned short* ax = isf32 ? (A + (size_t)rowA * 256 + 128 + lq * 8)
                                         : (xus + (size_t)rowA * 128 + lq * 8);
        f32x4 acc[8];
        #pragma unroll
        for (int t = 0; t < 8; t++) acc[t] = (f32x4){0.f, 0.f, 0.f, 0.f};
        #pragma unroll
        for (int s = 0; s < 8; s++) {
            bf16x8 a = (s < 4) ? *(const bf16x8*)(amean + s * 32)
                               : *(const bf16x8*)(ax + (s - 4) * 32);
            #pragma unroll
            for (int t = 0; t < 8; t++) {
                bf16x8 b = *(const bf16x8*)(lds + ((t * 8 + s) * 64 + lane) * 8);
                acc[t] = __builtin_amdgcn_mfma_f32_16x16x32_bf16(a, b, acc[t], 0, 0, 0);
            }
        }
        #pragma unroll
        for (int t = 0; t < 8; t++) {
            int col = t * 16 + lm;
            #pragma unroll
            for (int r = 0; r < 4; r++) {
                int ro = m0 + wave * 16 + lq * 4 + r;
                if (ro < N_NODES) {
                    float v = acc[t][r] + bv[t];
                    H[(size_t)ro * DIM + col] = v;
                    st1[t] += v;
                    st2[t] += v * v;
                }
            }
        }
    }
    // block-level stats reduce
    #pragma unroll
    for (int t = 0; t < 8; t++) {
        atomicAdd(&sstat[0][t * 16 + lm], st1[t]);
        atomicAdd(&sstat[1][t * 16 + lm], st2[t]);
    }
    __syncthreads();
    if (threadIdx.x < 128) {
        atomicAdd(&gsum[threadIdx.x], sstat[0][threadIdx.x]);
        atomicAdd(&gsumsq[threadIdx.x], sstat[1][threadIdx.x]);
    }
}

// ---- normalize + LeakyReLU, write out (dtype per flag) ----
__global__ __launch_bounds__(256) void bn_norm_kernel(const float* H, const float* gsum,
                                                      const float* gsumsq, const void* gamma,
                                                      const void* beta, void* out,
                                                      const int* flags) {
    __shared__ float sc[128], sh[128];
    int isf32 = flags[1];
    int tid = threadIdx.x;
    if (tid < 128) {
        const float invN = 1.0f / (float)N_NODES;
        float mu = gsum[tid] * invN;
        float var = gsumsq[tid] * invN - mu * mu;
        float rstd = rsqrtf(var + BN_EPS);
        float g = loadS(gamma, tid, isf32);
        float b = loadS(beta, tid, isf32);
        sc[tid] = g * rstd;
        sh[tid] = b - mu * g * rstd;
    }
    __syncthreads();
    size_t idx = (size_t)blockIdx.x * 256 + tid;
    size_t i4 = idx * 4;
    if (i4 >= (size_t)N_NODES * DIM) return;
    float4 h = *(const float4*)(H + i4);
    int c0 = (int)(i4 & 127);
    float o0 = h.x * sc[c0 + 0] + sh[c0 + 0];
    float o1 = h.y * sc[c0 + 1] + sh[c0 + 1];
    float o2 = h.z * sc[c0 + 2] + sh[c0 + 2];
    float o3 = h.w * sc[c0 + 3] + sh[c0 + 3];
    o0 = (o0 >= 0.f) ? o0 : ALPHA * o0;
    o1 = (o1 >= 0.f) ? o1 : ALPHA * o1;
    o2 = (o2 >= 0.f) ? o2 : ALPHA * o2;
    o3 = (o3 >= 0.f) ? o3 : ALPHA * o3;
    if (isf32) {
        float4 o = make_float4(o0, o1, o2, o3);
        *(float4*)((float*)out + i4) = o;
    } else {
        uint2 u;
        u.x = (unsigned int)f2bf(o0) | ((unsigned int)f2bf(o1) << 16);
        u.y = (unsigned int)f2bf(o2) | ((unsigned int)f2bf(o3) << 16);
        *(uint2*)((unsigned short*)out + i4) = u;
    }
}

extern "C" void kernel_launch(void* const* d_in, const int* in_sizes, int n_in,
                              void* d_out, int out_size, void* d_ws, size_t ws_size,
                              hipStream_t stream) {
    const void* x     = d_in[0];
    const void* eidx  = d_in[1];
    const void* W_l   = d_in[2];
    const void* b_l   = d_in[3];
    const void* W_r   = d_in[4];
    const void* gamma = d_in[5];
    const void* beta  = d_in[6];
    char* ws = (char*)d_ws;
    int* flags = (int*)(ws + OFF_FLAGS);
    float* gsum = (float*)(ws + OFF_SUM);
    float* gsumsq = (float*)(ws + OFF_SUMSQ);
    int* blockTot = (int*)(ws + OFF_BLOCKTOT);
    int* cnt = (int*)(ws + OFF_CNT);
    int* offs = (int*)(ws + OFF_OFFS);
    int* wptr = (int*)(ws + OFF_WPTR);
    int* csr = (int*)(ws + OFF_CSR);
    unsigned short* bfrag = (unsigned short*)(ws + OFF_BFRAG);
    unsigned short* A = (unsigned short*)(ws + OFF_A);
    float* H = (float*)(ws + OFF_H);

    // zero flags/sums/blockTot/cnt
    hipMemsetAsync(ws, 0, OFF_CNT + (size_t)N_NODES * sizeof(int), stream);
    detect_kernel<<<1, 1024, 0, stream>>>((const unsigned int*)x, (const unsigned int*)eidx, flags);
    hist_kernel<<<N_EDGES / 256, 256, 0, stream>>>(eidx, cnt, flags);
    scan1_kernel<<<49, 256, 0, stream>>>(cnt, offs, blockTot);
    scan2_kernel<<<1, 64, 0, stream>>>(blockTot, 49);
    scan3_kernel<<<(N_NODES + 255) / 256, 256, 0, stream>>>(offs, blockTot, wptr);
    fill_kernel<<<N_EDGES / 256, 256, 0, stream>>>(eidx, wptr, csr, flags);
    bprep_kernel<<<128, 256, 0, stream>>>(W_l, W_r, bfrag, flags);
    agg_kernel<<<N_NODES / 4, 256, 0, stream>>>(x, csr, offs, cnt, A, flags);
    gemm_kernel<<<512, 256, 0, stream>>>(A, x, bfrag, b_l, H, gsum, gsumsq, flags);
    bn_norm_kernel<<<12500, 256, 0, stream>>>(H, gsum, gsumsq, gamma, beta, d_out, flags);
}